// Round 11
// baseline (973.309 us; speedup 1.0000x reference)
//
#include <hip/hip_runtime.h>
#include <hip/hip_fp16.h>

#define NB 8
#define CAP 128
#define NFEAT 704
#define MSLICE 8            // node slices per (batch,k) in moments
#define PSLICE (MSLICE * 4) // partial slots = slices * subs

// ---------------- setup kernels ----------------

__global__ void count_edges(const int* __restrict__ ei, int E, int* __restrict__ cnt) {
    int e = blockIdx.x * blockDim.x + threadIdx.x;
    if (e < E) atomicAdd(&cnt[ei[E + e]], 1);
}

__global__ void compute_dinv(const int* __restrict__ cnt, float* __restrict__ dinv, int n) {
    int v = blockIdx.x * blockDim.x + threadIdx.x;
    if (v < n) dinv[v] = rsqrtf((float)(cnt[v] + 1));  // +1 self-loop; always > 0
}

// packed edge: low 16 = src node (N < 65536), high 16 = f16 weight
__global__ void fill_edges(const int* __restrict__ ei, int E, const float* __restrict__ dinv,
                           int* __restrict__ cursor, unsigned int* __restrict__ pairs) {
    int e = blockIdx.x * blockDim.x + threadIdx.x;
    if (e < E) {
        int r = ei[e], c = ei[E + e];
        int pos = atomicAdd(&cursor[c], 1);
        if (pos < CAP) {
            float w = dinv[r] * dinv[c];
            __half hw = __float2half_rn(w);
            unsigned short hb = *reinterpret_cast<unsigned short*>(&hw);
            pairs[(size_t)c * CAP + pos] = (unsigned int)(r & 0xFFFF) | ((unsigned int)hb << 16);
        }
    }
}

// pad each node's edge list to a multiple of 8 with zero-weight edges (src 0, w +0)
__global__ void pad_edges(const int* __restrict__ cnt, unsigned int* __restrict__ pairs, int n) {
    int v = blockIdx.x * blockDim.x + threadIdx.x;
    if (v >= n) return;
    int c = min(cnt[v], CAP);
    int c8 = (c + 7) & ~7;
    for (int j = c; j < c8; ++j) pairs[(size_t)v * CAP + j] = 0u;
}

// batch is SORTED: boundaries, no atomics
__global__ void batch_bounds(const int* __restrict__ batch, int n, int* __restrict__ boff) {
    int i = blockIdx.x * blockDim.x + threadIdx.x;
    if (i >= n) return;
    int b = batch[i];
    int pb = (i == 0) ? -1 : batch[i - 1];
    for (int k = pb + 1; k <= b; ++k) boff[k] = i;
    if (i == n - 1) {
        for (int k = b + 1; k <= NB; ++k) boff[k] = n;
    }
}

__global__ void convert_f16(const float* __restrict__ x, unsigned short* __restrict__ xh, int n) {
    int i = blockIdx.x * blockDim.x + threadIdx.x;
    if (i < n) {
        __half h = __float2half_rn(x[i]);
        xh[i] = *reinterpret_cast<unsigned short*>(&h);
    }
}

// ---------------- cascade (U1 L1-units + U2 L2-units per wave, one wave per node) --------
// h_out = 0.5*((1+dinv^2)*h_in + sum w*h_in[src]); gathers read fp16 MIRRORS
// (128 B/row/unit); self term, state, diffs fp32.
// Lane l: edge-phase sub = l>>3 (8 edges/round), channel octet cg = l&7
// (8 fp16 ch = one uint4 = 16 B gather per unit per edge). Pair word is a
// broadcast dword pb[j+sub], next round prefetched. Reduce: shfl_xor {8,16,32}.
// L1 snap s=1, diffs {2,4,8,16}->S1 slots 0..3 (+f16 S1h slots 0..2).
// L2 unit u: snap s=2<<u, diffs later {4,8,16}->S2 slots.
// Instantiations: <1,0> L1-only, <1,3> fused (L1 step s1 = s2+8), <0,3> L2-only.

__device__ __forceinline__ float h2f16(unsigned short h) {
    __half hh = *reinterpret_cast<__half*>(&h);
    return __half2float(hh);
}

__device__ __forceinline__ void fma_h8(float w, uint4 m, float* a) {
    float2 f0 = __half22float2(*reinterpret_cast<__half2*>(&m.x));
    float2 f1 = __half22float2(*reinterpret_cast<__half2*>(&m.y));
    float2 f2 = __half22float2(*reinterpret_cast<__half2*>(&m.z));
    float2 f3 = __half22float2(*reinterpret_cast<__half2*>(&m.w));
    a[0] += w * f0.x; a[1] += w * f0.y; a[2] += w * f1.x; a[3] += w * f1.y;
    a[4] += w * f2.x; a[5] += w * f2.y; a[6] += w * f3.x; a[7] += w * f3.y;
}

__device__ __forceinline__ uint4 pack_h8(const float* v) {
    __half2 p0 = __float22half2_rn(make_float2(v[0], v[1]));
    __half2 p1 = __float22half2_rn(make_float2(v[2], v[3]));
    __half2 p2 = __float22half2_rn(make_float2(v[4], v[5]));
    __half2 p3 = __float22half2_rn(make_float2(v[6], v[7]));
    uint4 r;
    r.x = *reinterpret_cast<unsigned int*>(&p0);
    r.y = *reinterpret_cast<unsigned int*>(&p1);
    r.z = *reinterpret_cast<unsigned int*>(&p2);
    r.w = *reinterpret_cast<unsigned int*>(&p3);
    return r;
}

template <int U1, int U2>
__global__ __launch_bounds__(256) void cascade_k(
    const float* __restrict__ self1, const unsigned short* __restrict__ mir1,
    float* __restrict__ state1o, unsigned short* __restrict__ mir1o,
    float* __restrict__ prev1, int s1,
    const float* __restrict__ self2, int sstride2, long usz2,
    const unsigned short* __restrict__ mir2, long musz2,
    float* __restrict__ state2o, unsigned short* __restrict__ mir2o,
    float* __restrict__ prev2, int s2,
    const unsigned int* __restrict__ pairs, const int* __restrict__ cnt,
    const float* __restrict__ dinv, int n,
    float* __restrict__ S1, unsigned short* __restrict__ S1h,
    float* __restrict__ S2)
{
    int lane = threadIdx.x & 63, widx = threadIdx.x >> 6;
    int node = blockIdx.x * 4 + widx;
    if (node >= n) return;
    node = __builtin_amdgcn_readfirstlane(node);

    int deg = min(cnt[node], CAP);
    int deg8 = (deg + 7) & ~7;
    float dv = dinv[node];
    float selfw = 1.f + dv * dv;

    int sub = lane >> 3;   // edge phase: 8 edges per round
    int cg  = lane & 7;    // channel octet: ch cg*8 .. +7

    const unsigned int* pb = pairs + (size_t)node * CAP;

    float a1[U1 ? U1 : 1][8], a2[U2 ? U2 : 1][8];
#pragma unroll
    for (int u = 0; u < (U1 ? U1 : 1); ++u)
#pragma unroll
        for (int k = 0; k < 8; ++k) a1[u][k] = 0.f;
#pragma unroll
    for (int u = 0; u < (U2 ? U2 : 1); ++u)
#pragma unroll
        for (int k = 0; k < 8; ++k) a2[u][k] = 0.f;

    if (deg8 > 0) {
        unsigned int e = pb[sub];
        int j = 0;
        while (true) {
            int jn = j + 8;
            bool more = jn < deg8;
            unsigned int en = 0;
            if (more) en = pb[jn + sub];   // prefetch next round's pair word
            int   src = (int)(e & 0xFFFFu);
            float w   = h2f16((unsigned short)(e >> 16));
            uint4 g1, g2[U2 ? U2 : 1];
            if (U1)
                g1 = *reinterpret_cast<const uint4*>(mir1 + (size_t)src * 64 + cg * 8);
#pragma unroll
            for (int u = 0; u < U2; ++u)
                g2[u] = *reinterpret_cast<const uint4*>(mir2 + (size_t)u * musz2 + (size_t)src * 64 + cg * 8);
            if (U1) fma_h8(w, g1, a1[0]);
#pragma unroll
            for (int u = 0; u < U2; ++u) fma_h8(w, g2[u], a2[u]);
            if (!more) break;
            e = en; j = jn;
        }
    }

    // reduce the 8 edge-phases: lanes {cg, cg+8, ..., cg+56} share channels
#pragma unroll
    for (int m = 8; m <= 32; m <<= 1) {
#pragma unroll
        for (int u = 0; u < U1; ++u)
#pragma unroll
            for (int k = 0; k < 8; ++k) a1[u][k] += __shfl_xor(a1[u][k], m, 64);
#pragma unroll
        for (int u = 0; u < U2; ++u)
#pragma unroll
            for (int k = 0; k < 8; ++k) a2[u][k] += __shfl_xor(a2[u][k], m, 64);
    }

    if (lane < 8) {
        if (U1) {
            const float* srow = self1 + (size_t)node * 64 + cg * 8;
            float4 h0 = *reinterpret_cast<const float4*>(srow);
            float4 h1 = *reinterpret_cast<const float4*>(srow + 4);
            float v[8];
            v[0] = 0.5f * (selfw * h0.x + a1[0][0]);
            v[1] = 0.5f * (selfw * h0.y + a1[0][1]);
            v[2] = 0.5f * (selfw * h0.z + a1[0][2]);
            v[3] = 0.5f * (selfw * h0.w + a1[0][3]);
            v[4] = 0.5f * (selfw * h1.x + a1[0][4]);
            v[5] = 0.5f * (selfw * h1.y + a1[0][5]);
            v[6] = 0.5f * (selfw * h1.z + a1[0][6]);
            v[7] = 0.5f * (selfw * h1.w + a1[0][7]);
            size_t oidx = (size_t)node * 64 + cg * 8;
            *reinterpret_cast<float4*>(state1o + oidx)     = make_float4(v[0], v[1], v[2], v[3]);
            *reinterpret_cast<float4*>(state1o + oidx + 4) = make_float4(v[4], v[5], v[6], v[7]);
            *reinterpret_cast<uint4*>(mir1o + oidx) = pack_h8(v);
            float* prow = prev1 + oidx;
            if (s1 == 1) {
                *reinterpret_cast<float4*>(prow)     = make_float4(v[0], v[1], v[2], v[3]);
                *reinterpret_cast<float4*>(prow + 4) = make_float4(v[4], v[5], v[6], v[7]);
            } else if (s1 == 2 || s1 == 4 || s1 == 8 || s1 == 16) {
                float4 p0 = *reinterpret_cast<const float4*>(prow);
                float4 p1 = *reinterpret_cast<const float4*>(prow + 4);
                *reinterpret_cast<float4*>(prow)     = make_float4(v[0], v[1], v[2], v[3]);
                *reinterpret_cast<float4*>(prow + 4) = make_float4(v[4], v[5], v[6], v[7]);
                float d[8];
                d[0] = fabsf(v[0] - p0.x); d[1] = fabsf(v[1] - p0.y);
                d[2] = fabsf(v[2] - p0.z); d[3] = fabsf(v[3] - p0.w);
                d[4] = fabsf(v[4] - p1.x); d[5] = fabsf(v[5] - p1.y);
                d[6] = fabsf(v[6] - p1.z); d[7] = fabsf(v[7] - p1.w);
                int slot = (s1 == 2) ? 0 : (s1 == 4) ? 1 : (s1 == 8) ? 2 : 3;
                float* drow = S1 + (size_t)node * 256 + slot * 64 + cg * 8;
                *reinterpret_cast<float4*>(drow)     = make_float4(d[0], d[1], d[2], d[3]);
                *reinterpret_cast<float4*>(drow + 4) = make_float4(d[4], d[5], d[6], d[7]);
                if (slot < 3)
                    *reinterpret_cast<uint4*>(S1h + (size_t)slot * n * 64 + oidx) = pack_h8(d);
            }
        }
#pragma unroll
        for (int u = 0; u < U2; ++u) {
            const float* srow = self2 + (size_t)u * usz2 + (size_t)node * sstride2 + cg * 8;
            float4 h0 = *reinterpret_cast<const float4*>(srow);
            float4 h1 = *reinterpret_cast<const float4*>(srow + 4);
            float v[8];
            v[0] = 0.5f * (selfw * h0.x + a2[u][0]);
            v[1] = 0.5f * (selfw * h0.y + a2[u][1]);
            v[2] = 0.5f * (selfw * h0.z + a2[u][2]);
            v[3] = 0.5f * (selfw * h0.w + a2[u][3]);
            v[4] = 0.5f * (selfw * h1.x + a2[u][4]);
            v[5] = 0.5f * (selfw * h1.y + a2[u][5]);
            v[6] = 0.5f * (selfw * h1.z + a2[u][6]);
            v[7] = 0.5f * (selfw * h1.w + a2[u][7]);
            size_t oidx = (size_t)u * n * 64 + (size_t)node * 64 + cg * 8;
            *reinterpret_cast<float4*>(state2o + oidx)     = make_float4(v[0], v[1], v[2], v[3]);
            *reinterpret_cast<float4*>(state2o + oidx + 4) = make_float4(v[4], v[5], v[6], v[7]);
            *reinterpret_cast<uint4*>(mir2o + oidx) = pack_h8(v);
            int snap = 2 << u;
            float* prow = prev2 + oidx;
            if (s2 == snap) {
                *reinterpret_cast<float4*>(prow)     = make_float4(v[0], v[1], v[2], v[3]);
                *reinterpret_cast<float4*>(prow + 4) = make_float4(v[4], v[5], v[6], v[7]);
            } else if (s2 > snap && (s2 == 4 || s2 == 8 || s2 == 16)) {
                float4 p0 = *reinterpret_cast<const float4*>(prow);
                float4 p1 = *reinterpret_cast<const float4*>(prow + 4);
                *reinterpret_cast<float4*>(prow)     = make_float4(v[0], v[1], v[2], v[3]);
                *reinterpret_cast<float4*>(prow + 4) = make_float4(v[4], v[5], v[6], v[7]);
                float d[8];
                d[0] = fabsf(v[0] - p0.x); d[1] = fabsf(v[1] - p0.y);
                d[2] = fabsf(v[2] - p0.z); d[3] = fabsf(v[3] - p0.w);
                d[4] = fabsf(v[4] - p1.x); d[5] = fabsf(v[5] - p1.y);
                d[6] = fabsf(v[6] - p1.z); d[7] = fabsf(v[7] - p1.w);
                int slt;
                if (u == 0)      slt = (s2 == 4) ? 0 : (s2 == 8) ? 1 : 3;
                else if (u == 1) slt = (s2 == 8) ? 2 : 4;
                else             slt = 5;
                float* drow = S2 + (size_t)node * 384 + slt * 64 + cg * 8;
                *reinterpret_cast<float4*>(drow)     = make_float4(d[0], d[1], d[2], d[3]);
                *reinterpret_cast<float4*>(drow + 4) = make_float4(d[4], d[5], d[6], d[7]);
            }
        }
    }
}

// ---------------- moments (coalesced two-stage, no atomics) ----------------

__global__ __launch_bounds__(256) void moments_part(
    const float* __restrict__ x, const float* __restrict__ S1,
    const float* __restrict__ S2, const int* __restrict__ boff,
    double* __restrict__ part)
{
    int bid = blockIdx.x;                    // b * (11*MSLICE) + k * MSLICE + slice
    int slice = bid % MSLICE;
    int k = (bid / MSLICE) % 11;
    int b = bid / (11 * MSLICE);
    int c = threadIdx.x & 63, sub = threadIdx.x >> 6;

    const float* base; int stride;
    if (k == 0)      { base = x  + c;                stride = 64;  }
    else if (k <= 4) { base = S1 + (k - 1) * 64 + c; stride = 256; }
    else             { base = S2 + (k - 5) * 64 + c; stride = 384; }

    int s0 = boff[b], s1e = boff[b + 1];
    int cntb = s1e - s0;
    int per = (cntb + MSLICE - 1) / MSLICE;
    int i0 = s0 + slice * per;
    int i1 = min(s1e, i0 + per);

    double a1 = 0, a2 = 0, a3 = 0, a4 = 0;
    for (int i = i0 + sub; i < i1; i += 4) {
        double v = (double)base[(size_t)i * stride];
        double qq = v * v;
        a1 += v; a2 += qq; a3 += qq * v; a4 += qq * qq;
    }
    int f = k * 64 + c;
    double* qp = part + ((((size_t)slice * 4 + sub) * NB + b) * NFEAT + f) * 4;
    qp[0] = a1; qp[1] = a2; qp[2] = a3; qp[3] = a4;
}

__global__ void finalize_k(const double* __restrict__ part, const int* __restrict__ boff,
                           const float* __restrict__ W, float* __restrict__ out) {
    int i = blockIdx.x * blockDim.x + threadIdx.x;
    if (i < NB * NFEAT) {
        int b = i / NFEAT, f = i % NFEAT;
        double s1 = 0, s2 = 0, s3 = 0, s4 = 0;
        for (int s = 0; s < PSLICE; ++s) {
            const double* qp = part + (((size_t)s * NB + b) * NFEAT + f) * 4;
            s1 += qp[0]; s2 += qp[1]; s3 += qp[2]; s4 += qp[3];
        }
        double cn = (double)max(boff[b + 1] - boff[b], 1);
        double mean = s1 / cn;
        double e2 = s2 / cn, e3 = s3 / cn, e4 = s4 / cn;
        double var = e2 - mean * mean;
        double m3 = e3 - 3.0 * mean * e2 + 2.0 * mean * mean * mean;
        double m4 = e4 - 4.0 * mean * e3 + 6.0 * mean * mean * e2 - 3.0 * mean * mean * mean * mean;
        float skew, kurt;
        if (var > 0.0) {
            double vs = var * sqrt(var);
            skew = (float)(m3 / vs);
            kurt = (float)(m4 / (var * var));
        } else {
            skew = 0.f; kurt = -3.f;
        }
        out[b * 2816 + f]        = (float)mean;
        out[b * 2816 + 704 + f]  = (float)var;
        out[b * 2816 + 1408 + f] = skew;
        out[b * 2816 + 2112 + f] = kurt;
    } else if (i < NB * NFEAT + 68) {
        int j = i - NB * NFEAT;
        out[NB * 2816 + j] = W[j];
    }
}

// ---------------- launch ----------------

extern "C" void kernel_launch(void* const* d_in, const int* in_sizes, int n_in,
                              void* d_out, int out_size, void* d_ws, size_t ws_size,
                              hipStream_t stream) {
    const float* x     = (const float*)d_in[0];
    const int*   ei    = (const int*)d_in[1];
    const int*   batch = (const int*)d_in[2];
    const float* W     = (const float*)d_in[3];
    int N = in_sizes[0] / 64;   // 20000
    int E = in_sizes[1] / 2;    // 640000
    float* out = (float*)d_out;

    char* p = (char*)d_ws;
    auto alloc = [&](size_t bytes) { char* r = p; p += (bytes + 255) & ~255ULL; return r; };
    float* dinv  = (float*)alloc((size_t)N * 4);
    int*   cnt   = (int*)alloc((size_t)N * 4);
    int*   cursor= (int*)alloc((size_t)N * 4);
    int*   boff  = (int*)alloc((NB + 1) * 4);
    double* part = (double*)alloc((size_t)PSLICE * NB * NFEAT * 4 * 8);
    unsigned int* pairs = (unsigned int*)alloc((size_t)N * CAP * 4);
    float* S1    = (float*)alloc((size_t)N * 256 * 4);
    float* S2    = (float*)alloc((size_t)N * 384 * 4);
    unsigned short* S1h = (unsigned short*)alloc((size_t)3 * N * 64 * 2);
    unsigned short* xh  = (unsigned short*)alloc((size_t)N * 64 * 2);
    float* b1A   = (float*)alloc((size_t)N * 64 * 4);
    float* b1B   = (float*)alloc((size_t)N * 64 * 4);
    unsigned short* h1A = (unsigned short*)alloc((size_t)N * 64 * 2);
    unsigned short* h1B = (unsigned short*)alloc((size_t)N * 64 * 2);
    float* prev1 = (float*)alloc((size_t)N * 64 * 4);
    float* b2A   = (float*)alloc((size_t)3 * N * 64 * 4);
    float* b2B   = (float*)alloc((size_t)3 * N * 64 * 4);
    unsigned short* h2A = (unsigned short*)alloc((size_t)3 * N * 64 * 2);
    unsigned short* h2B = (unsigned short*)alloc((size_t)3 * N * 64 * 2);
    float* prev2 = (float*)alloc((size_t)3 * N * 64 * 4);

    hipMemsetAsync(cnt, 0, (size_t)N * 4, stream);
    hipMemsetAsync(cursor, 0, (size_t)N * 4, stream);

    count_edges<<<(E + 255) / 256, 256, 0, stream>>>(ei, E, cnt);
    compute_dinv<<<(N + 255) / 256, 256, 0, stream>>>(cnt, dinv, N);
    fill_edges<<<(E + 255) / 256, 256, 0, stream>>>(ei, E, dinv, cursor, pairs);
    pad_edges<<<(N + 255) / 256, 256, 0, stream>>>(cnt, pairs, N);
    batch_bounds<<<(N + 255) / 256, 256, 0, stream>>>(batch, N, boff);
    convert_f16<<<(N * 64 + 255) / 256, 256, 0, stream>>>(x, xh, N * 64);

    long nu = (long)N * 64;
    int cgrid = (N + 3) / 4;

    // ---- phase A: L1 steps 1..8 (snap s=1; diffs s=2,4,8 -> S1 slots 0..2 + S1h) ----
    for (int s = 1; s <= 8; ++s) {
        const float* si = (s == 1) ? x  : ((s & 1) ? b1B : b1A);
        const unsigned short* mi = (s == 1) ? xh : ((s & 1) ? h1B : h1A);
        float* so = (s & 1) ? b1A : b1B;
        unsigned short* mo = (s & 1) ? h1A : h1B;
        cascade_k<1, 0><<<cgrid, 256, 0, stream>>>(
            si, mi, so, mo, prev1, s,
            nullptr, 0, 0, nullptr, 0, nullptr, nullptr, nullptr, 0,
            pairs, cnt, dinv, N, S1, S1h, S2);
    }

    // ---- phase B: fused — L1 step t=f+8 with L2 step f, f=1..8 ----
    for (int f = 1; f <= 8; ++f) {
        int t = f + 8;
        const float* s1i = ((t - 1) & 1) ? b1A : b1B;
        const unsigned short* m1i = ((t - 1) & 1) ? h1A : h1B;
        float* s1o = (t & 1) ? b1A : b1B;
        unsigned short* m1o = (t & 1) ? h1A : h1B;
        const float* s2i; int sstride2; long usz2;
        const unsigned short* m2i; long musz2;
        if (f == 1) { s2i = S1; sstride2 = 256; usz2 = 64; m2i = S1h; musz2 = nu; }
        else {
            s2i = ((f - 1) & 1) ? b2A : b2B; sstride2 = 64; usz2 = nu;
            m2i = ((f - 1) & 1) ? h2A : h2B; musz2 = nu;
        }
        float* s2o = (f & 1) ? b2A : b2B;
        unsigned short* m2o = (f & 1) ? h2A : h2B;
        cascade_k<1, 3><<<cgrid, 256, 0, stream>>>(
            s1i, m1i, s1o, m1o, prev1, t,
            s2i, sstride2, usz2, m2i, musz2, s2o, m2o, prev2, f,
            pairs, cnt, dinv, N, S1, S1h, S2);
    }

    // ---- phase C: L2-only steps 9..16 (diffs at 16 -> S2 slots 3,4,5) ----
    for (int s = 9; s <= 16; ++s) {
        const float* s2i = ((s - 1) & 1) ? b2A : b2B;
        const unsigned short* m2i = ((s - 1) & 1) ? h2A : h2B;
        float* s2o = (s & 1) ? b2A : b2B;
        unsigned short* m2o = (s & 1) ? h2A : h2B;
        cascade_k<0, 3><<<cgrid, 256, 0, stream>>>(
            nullptr, nullptr, nullptr, nullptr, nullptr, 0,
            s2i, 64, nu, m2i, nu, s2o, m2o, prev2, s,
            pairs, cnt, dinv, N, S1, S1h, S2);
    }

    moments_part<<<NB * 11 * MSLICE, 256, 0, stream>>>(x, S1, S2, boff, part);

    int fin_threads = NB * NFEAT + 68;
    finalize_k<<<(fin_threads + 255) / 256, 256, 0, stream>>>(part, boff, W, out);
}